// Round 24
// baseline (129.024 us; speedup 1.0000x reference)
//
#include <hip/hip_runtime.h>

#define DMODEL 1024
#define NHEADS 16
#define BATCH  2
#define SEQ    2048
#define MROWS  (BATCH * SEQ)   // 4096

typedef unsigned short u16;
typedef unsigned int   u32;
typedef __attribute__((ext_vector_type(8))) short short8v;   // 8 bf16
typedef __attribute__((ext_vector_type(4))) short short4v;   // 4 bf16 (8 B)
typedef __attribute__((ext_vector_type(4))) int   int4v;
typedef __attribute__((ext_vector_type(4))) float f32x4;

// 0.125 * log2(e): folds 1/sqrt(dk) and exp->exp2 into one constant
#define SCALE_LOG2E 0.18033688011112042f

__device__ inline float bf2f(u16 u) {
  union { u32 i; float f; } c; c.i = ((u32)u) << 16; return c.f;
}
__device__ inline u16 f2bf(float f) {  // round-to-nearest-even
  union { float f; u32 i; } c; c.f = f;
  u32 r = c.i + 0x7fffu + ((c.i >> 16) & 1u);
  return (u16)(r >> 16);
}
__device__ inline short8v ld8(const u16* p) { return *(const short8v*)p; }
__device__ inline short8v cvt8f(const float* p) {   // 8 f32 -> 8 bf16
  f32x4 v0 = *(const f32x4*)p;
  f32x4 v1 = *(const f32x4*)(p + 4);
  short8v r;
#pragma unroll
  for (int j = 0; j < 4; ++j) { r[j] = (short)f2bf(v0[j]); r[4 + j] = (short)f2bf(v1[j]); }
  return r;
}
__device__ inline void gload_lds16(const u16* g, u16* l) {
  __builtin_amdgcn_global_load_lds(
      (const __attribute__((address_space(1))) void*)g,
      (__attribute__((address_space(3))) void*)l, 16, 0, 0);
}
// raw v_exp_f32 (2^x)
__device__ inline float exp2raw(float x) { return __builtin_amdgcn_exp2f(x); }
// v_cvt_pk_bf16_f32: dst.lo16 = bf16(a), dst.hi16 = bf16(b)  [T12/m240 recipe]
__device__ inline u32 pkbf(float a, float b) {
  u32 d; asm("v_cvt_pk_bf16_f32 %0, %1, %2" : "=v"(d) : "v"(a), "v"(b));
  return d;
}

// XOR swizzle for [.][64]-u16 LDS tiles (128 B rows) — r8..r20-proven.
__device__ inline int swz(int idx) {
  return idx ^ ((((idx >> 6) ^ (idx >> 9)) & 7) << 3);
}

// ---------------------------------------------------------------------------
// One-pass f32 -> bf16 conversion (unchanged, green).
// ---------------------------------------------------------------------------
__global__ __launch_bounds__(256) void cvt_all(
    const float* __restrict__ xq, const float* __restrict__ xk,
    const float* __restrict__ xv, const float* __restrict__ wq,
    const float* __restrict__ wk, const float* __restrict__ wv,
    const float* __restrict__ wo, u16* __restrict__ dst)
{
  int b = blockIdx.x;
  const float* s;
  u16* d;
  int local;
  if (b < 6144) {
    int which = b >> 11;
    s = (which == 0) ? xq : (which == 1) ? xk : xv;
    d = dst + (long)which * 4194304;
    local = b & 2047;
  } else {
    int wb = b - 6144;
    int which = wb >> 9;
    s = (which == 0) ? wq : (which == 1) ? wk : (which == 2) ? wv : wo;
    d = dst + 12582912 + (long)which * 1048576;
    local = wb & 511;
  }
  const long idx = ((long)local * 256 + threadIdx.x) * 8;
  *(short8v*)(d + idx) = cvt8f(s + idx);
}

// ---------------------------------------------------------------------------
// Pure-bf16 NT GEMM — EXACT r20 (green): 2-phase dbuf, BK=64, 128x64 tile,
// z-indexed operand triples (merged projection dispatch).
// ---------------------------------------------------------------------------
__global__ __launch_bounds__(256) void gemm_bf(
    const u16* __restrict__ A0, const u16* __restrict__ A1, const u16* __restrict__ A2,
    const u16* __restrict__ W0, const u16* __restrict__ W1, const u16* __restrict__ W2,
    void* __restrict__ C0, void* __restrict__ C1, void* __restrict__ C2,
    const float* __restrict__ bias, int CF32, int Ndim, int Kdim)
{
  __shared__ __align__(16) u16 As[2][128 * 64];   // 2 x 16 KB
  __shared__ __align__(16) u16 Bs[2][64 * 64];    // 2 x  8 KB

  const int z = blockIdx.z;
  const u16* A = (z == 0) ? A0 : (z == 1) ? A1 : A2;
  const u16* W = (z == 0) ? W0 : (z == 1) ? W1 : W2;
  void* Craw   = (z == 0) ? C0 : (z == 1) ? C1 : C2;

  const int tid  = threadIdx.x;
  const int lane = tid & 63;
  const int w    = tid >> 6;
  const int wr   = w >> 1, wc = w & 1;
  const int r    = lane & 15, g = lane >> 4;

  const long brow = (long)blockIdx.x * 128;
  const long bcol = (long)blockIdx.y * 64;

  const int trow = tid >> 2;        // 0..63
  const int tk   = (tid & 3) * 8;   // 0,8,16,24

  const u16* Arow0 = A + (brow + trow) * (long)Kdim + tk;
  const u16* Arow1 = A + (brow + trow + 64) * (long)Kdim + tk;
  const u16* Wrow  = W + (bcol + trow) * (long)Kdim + tk;
  const int  woff  = w * 512;       // wave-uniform linear LDS dest (elems)

  f32x4 acc[4][2] = {};

  // prologue: stage k = 0..63 into buffer 0 (two 32-wide halves)
  gload_lds16(Arow0,      As[0] + woff);
  gload_lds16(Arow1,      As[0] + woff + 2048);
  gload_lds16(Arow0 + 32, As[0] + woff + 4096);
  gload_lds16(Arow1 + 32, As[0] + woff + 6144);
  gload_lds16(Wrow,       Bs[0] + woff);
  gload_lds16(Wrow + 32,  Bs[0] + woff + 2048);
  __syncthreads();   // drain vmcnt -> tile 0 visible

  int cur = 0;
  for (int k0 = 0; k0 < Kdim; k0 += 64) {
    if (k0 + 64 < Kdim) {
      const int kn = k0 + 64;
      gload_lds16(Arow0 + kn,      As[cur ^ 1] + woff);
      gload_lds16(Arow1 + kn,      As[cur ^ 1] + woff + 2048);
      gload_lds16(Arow0 + kn + 32, As[cur ^ 1] + woff + 4096);
      gload_lds16(Arow1 + kn + 32, As[cur ^ 1] + woff + 6144);
      gload_lds16(Wrow + kn,       Bs[cur ^ 1] + woff);
      gload_lds16(Wrow + kn + 32,  Bs[cur ^ 1] + woff + 2048);
    }

#pragma unroll
    for (int half = 0; half < 2; ++half) {
      const u16* Ah = As[cur] + half * 4096;
      const u16* Bh = Bs[cur] + half * 2048;
      short8v afr[4], bfr[2];
#pragma unroll
      for (int m = 0; m < 4; ++m)
        afr[m] = ld8(Ah + (wr * 64 + m * 16 + r) * 32 + g * 8);
#pragma unroll
      for (int n = 0; n < 2; ++n)
        bfr[n] = ld8(Bh + (wc * 32 + n * 16 + r) * 32 + g * 8);
#pragma unroll
      for (int m = 0; m < 4; ++m)
#pragma unroll
        for (int n = 0; n < 2; ++n)
          acc[m][n] = __builtin_amdgcn_mfma_f32_16x16x32_bf16(afr[m], bfr[n], acc[m][n], 0, 0, 0);
    }

    __syncthreads();   // next-tile loads drained; all readers of [cur] done
    cur ^= 1;
  }

#pragma unroll
  for (int n = 0; n < 2; ++n) {
    const long col = bcol + wc * 32 + n * 16 + r;
    const float bv = bias ? bias[col] : 0.0f;
#pragma unroll
    for (int m = 0; m < 4; ++m) {
#pragma unroll
      for (int r4 = 0; r4 < 4; ++r4) {
        const long row = brow + wr * 64 + m * 16 + g * 4 + r4;
        if (CF32) ((float*)Craw)[row * (long)Ndim + col] = acc[m][n][r4] + bv;
        else      ((u16*)Craw)[row * (long)Ndim + col]   = f2bf(acc[m][n][r4] + bv);
      }
    }
  }
}

// ---------------------------------------------------------------------------
// MFMA flash attention — EXACT r19 structure (best green, 68 us) + T5
// s_setprio around the MFMA clusters (waves within a tile are NOT lockstep:
// softmax-VALU and MFMA phases co-exist on a CU -> scheduler arbitration
// pays, per m191). Swapped QK^T, packed b64 P stores, XCD-pinned panels,
// 256 q-rows/block, dbuf K/V, max-free softmax.
// ---------------------------------------------------------------------------
__global__ __launch_bounds__(512) void attn_kernel(
    const u16* __restrict__ Q, const u16* __restrict__ K,
    const u16* __restrict__ V, const int* __restrict__ mask,
    u16* __restrict__ O)
{
  __shared__ __align__(16) u16 Ks[2][64 * 64];   // [key][d]   swizzled
  __shared__ __align__(16) u16 Vt[2][64 * 64];   // [d][key]   swizzled
  __shared__ __align__(16) u16 Ps[256 * 64];     // [q_local][key] swizzled

  const int tid  = threadIdx.x;
  const int lane = tid & 63;
  const int w    = tid >> 6;            // 0..7
  const int r    = lane & 15, g = lane >> 4;

  // XCD-aware decode: panels (b,h) pinned to one XCD (r18-proven)
  const int slot = blockIdx.x;          // 0..255
  const int p    = (slot & 7) + 8 * (slot >> 6);   // panel 0..31
  const int x    = (slot >> 3) & 7;                // q-tile 0..7
  const int h    = p & 15;
  const int b    = p >> 4;

  const long wq = (long)b * SEQ + (long)x * 256 + w * 32;

  short8v qf[2][2];
#pragma unroll
  for (int qt = 0; qt < 2; ++qt)
#pragma unroll
    for (int ks = 0; ks < 2; ++ks)
      qf[qt][ks] = ld8(Q + (wq + qt * 16 + r) * DMODEL + h * 64 + ks * 32 + g * 8);

  f32x4 of[2][4] = {};
  float lsum[2] = {0.f, 0.f};           // row-sum for q = wq + qt*16 + r

  const int trow = tid >> 3;            // 0..63 (full key coverage, 512 thr)
  const int td   = (tid & 7) * 8;       // 0..56

  const u16* Kb = K + (long)b * SEQ * DMODEL + h * 64;
  const u16* Vb = V + (long)b * SEQ * DMODEL + h * 64;
  const int* mb = mask + (long)b * SEQ;

  // prologue: stage tile 0 (each thread: one K row-piece, one V row-piece)
  {
    short8v k0v = ld8(Kb + (long)trow * DMODEL + td);
    short8v v0v = ld8(Vb + (long)trow * DMODEL + td);
    *(short8v*)(Ks[0] + swz(trow * 64 + td)) = k0v;
#pragma unroll
    for (int j = 0; j < 8; ++j)
      Vt[0][swz((td + j) * 64 + trow)] = (u16)v0v[j];
  }

  int cur = 0;

  for (int t = 0; t < SEQ / 64; ++t) {
    const int kt0 = t * 64;
    const bool more = (t < SEQ / 64 - 1);

    // mask for this tile: 4 consecutive keys per kt (this lane's g-group)
    int4v keepc[4];
#pragma unroll
    for (int kt = 0; kt < 4; ++kt)
      keepc[kt] = *(const int4v*)(mb + kt0 + kt * 16 + g * 4);

    // issue next-tile global loads early (hide HBM/L2 latency under compute)
    short8v nk0, nv0;
    if (more) {
      nk0 = ld8(Kb + (long)(kt0 + 64 + trow) * DMODEL + td);
      nv0 = ld8(Vb + (long)(kt0 + 64 + trow) * DMODEL + td);
    }

    __syncthreads();   // staged tile [cur] visible; prev-iter readers done

    const u16* Kc = Ks[cur];
    const u16* Vc = Vt[cur];

    // S^T = K Q^T (swapped operands): lane holds S[q=r][key=kt*16+g*4+r4]
    f32x4 sf[2][4] = {};
#pragma unroll
    for (int ks = 0; ks < 2; ++ks) {
      short8v kf[4];
#pragma unroll
      for (int kt = 0; kt < 4; ++kt)
        kf[kt] = ld8(Kc + swz((kt * 16 + r) * 64 + ks * 32 + g * 8));
      __builtin_amdgcn_s_setprio(1);
#pragma unroll
      for (int qt = 0; qt < 2; ++qt)
#pragma unroll
        for (int kt = 0; kt < 4; ++kt)
          sf[qt][kt] = __builtin_amdgcn_mfma_f32_16x16x32_bf16(kf[kt], qf[qt][ks], sf[qt][kt], 0, 0, 0);
      __builtin_amdgcn_s_setprio(0);
    }

    // max-free softmax: 4 consecutive keys -> one packed b64 write per kt
#pragma unroll
    for (int qt = 0; qt < 2; ++qt) {
      const int prow = (w * 32 + qt * 16 + r) * 64;
#pragma unroll
      for (int kt = 0; kt < 4; ++kt) {
        float p0 = keepc[kt][0] ? exp2raw(sf[qt][kt][0] * SCALE_LOG2E) : 0.f;
        float p1 = keepc[kt][1] ? exp2raw(sf[qt][kt][1] * SCALE_LOG2E) : 0.f;
        float p2 = keepc[kt][2] ? exp2raw(sf[qt][kt][2] * SCALE_LOG2E) : 0.f;
        float p3 = keepc[kt][3] ? exp2raw(sf[qt][kt][3] * SCALE_LOG2E) : 0.f;
        union { u32 u[2]; short4v s; } pk;
        pk.u[0] = pkbf(p0, p1);
        pk.u[1] = pkbf(p2, p3);
        *(short4v*)(Ps + swz(prow + kt * 16 + g * 4)) = pk.s;
        lsum[qt] += (p0 + p1) + (p2 + p3);
      }
    }

    // O += P V  (vb reads shared by both q-tiles; same-wave Ps write->read)
#pragma unroll
    for (int ks = 0; ks < 2; ++ks) {
      short8v vb[4];
#pragma unroll
      for (int dt = 0; dt < 4; ++dt)
        vb[dt] = ld8(Vc + swz((dt * 16 + r) * 64 + ks * 32 + g * 8));
#pragma unroll
      for (int qt = 0; qt < 2; ++qt) {
        short8v pa = ld8(Ps + swz((w * 32 + qt * 16 + r) * 64 + ks * 32 + g * 8));
        __builtin_amdgcn_s_setprio(1);
#pragma unroll
        for (int dt = 0; dt < 4; ++dt)
          of[qt][dt] = __builtin_amdgcn_mfma_f32_16x16x32_bf16(pa, vb[dt], of[qt][dt], 0, 0, 0);
        __builtin_amdgcn_s_setprio(0);
      }
    }

    // stage tile t+1 into the other buffer
    if (more) {
      *(short8v*)(Ks[cur ^ 1] + swz(trow * 64 + td)) = nk0;
#pragma unroll
      for (int j = 0; j < 8; ++j)
        Vt[cur ^ 1][swz((td + j) * 64 + trow)] = (u16)nv0[j];
      cur ^= 1;
    }
  }

  // denominators: total(q=r) = reduce over g-groups; fetch totals for this
  // lane's 4 output rows (q = g*4 + r4) from lanes 0..15 (r12/r19-proven).
#pragma unroll
  for (int qt = 0; qt < 2; ++qt) {
    float s = lsum[qt];
    s += __shfl_xor(s, 16);
    s += __shfl_xor(s, 32);
#pragma unroll
    for (int r4 = 0; r4 < 4; ++r4) {
      const float d = __shfl(s, g * 4 + r4);
      const float rcp = (d > 0.f) ? (1.0f / d) : 0.0f;
#pragma unroll
      for (int dt = 0; dt < 4; ++dt) {
        const long row = wq + qt * 16 + g * 4 + r4;
        const int  col = h * 64 + dt * 16 + r;
        O[row * DMODEL + col] = f2bf(of[qt][dt][r4] * rcp);
      }
    }
  }
}

// ---------------------------------------------------------------------------
extern "C" void kernel_launch(void* const* d_in, const int* in_sizes, int n_in,
                              void* d_out, int out_size, void* d_ws, size_t ws_size,
                              hipStream_t stream) {
  const float* q_in = (const float*)d_in[0];
  const float* k_in = (const float*)d_in[1];
  const float* v_in = (const float*)d_in[2];
  const int*   mask = (const int*)d_in[3];
  const float* w_q  = (const float*)d_in[4];
  const float* w_k  = (const float*)d_in[5];
  const float* w_v  = (const float*)d_in[6];
  const float* w_o  = (const float*)d_in[7];
  const float* b_o  = (const float*)d_in[8];

  // ws layout (32 MB): [Xq 8M][Xk 8M][Xv 8M][WQ 2M][WK 2M][WV 2M][WO 2M]
  u16* S  = (u16*)d_ws;
  u16* Xq = S;
  u16* Xk = S + 4194304;
  u16* Xv = S + 8388608;
  u16* WQ = S + 12582912;
  u16* WK = S + 13631488;
  u16* WV = S + 14680064;
  u16* WO = S + 15728640;
  u16* Qw = (u16*)d_out;   // Q-proj lives in d_out until the final GEMM
  u16* Kw = Xq;            // K-proj overwrites Xq (dead after Q-proj)
  u16* Vw = Xk;            // V-proj overwrites Xk (dead after K-proj)
  u16* Cw = Xv;            // ctx overwrites Xv (dead after V-proj)

  dim3 blk(256);

  cvt_all<<<dim3(8192), blk, 0, stream>>>(q_in, k_in, v_in, w_q, w_k, w_v, w_o, S);

  // all three projections in ONE dispatch (z selects operand triple)
  dim3 pgrid(MROWS / 128, DMODEL / 64, 3);   // (32, 16, 3)
  gemm_bf<<<pgrid, blk, 0, stream>>>(Xq, Xk, Xv, WQ, WK, WV,
                                     Qw, Kw, Vw, nullptr, 0, DMODEL, DMODEL);

  // 256 blocks (1/CU), 512 threads; XCD-aware slot decode inside
  attn_kernel<<<dim3(256), dim3(512), 0, stream>>>(Qw, Kw, Vw, mask, Cw);

  dim3 ggrid(MROWS / 128, DMODEL / 64, 1);
  gemm_bf<<<ggrid, blk, 0, stream>>>(Cw, Cw, Cw, WO, WO, WO,
                                     (float*)d_out, (float*)d_out, (float*)d_out,
                                     b_o, 1, DMODEL, DMODEL);
}

// Round 25
// 123.986 us; speedup vs baseline: 1.0406x; 1.0406x over previous
//
#include <hip/hip_runtime.h>

#define DMODEL 1024
#define NHEADS 16
#define BATCH  2
#define SEQ    2048
#define MROWS  (BATCH * SEQ)   // 4096

typedef unsigned short u16;
typedef unsigned int   u32;
typedef __attribute__((ext_vector_type(8))) short short8v;   // 8 bf16
typedef __attribute__((ext_vector_type(4))) short short4v;   // 4 bf16 (8 B)
typedef __attribute__((ext_vector_type(4))) int   int4v;
typedef __attribute__((ext_vector_type(4))) float f32x4;

// 0.125 * log2(e): folded into the Q projection epilogue (r25)
#define SCALE_LOG2E 0.18033688011112042f

__device__ inline float bf2f(u16 u) {
  union { u32 i; float f; } c; c.i = ((u32)u) << 16; return c.f;
}
__device__ inline u16 f2bf(float f) {  // round-to-nearest-even
  union { float f; u32 i; } c; c.f = f;
  u32 r = c.i + 0x7fffu + ((c.i >> 16) & 1u);
  return (u16)(r >> 16);
}
__device__ inline short8v ld8(const u16* p) { return *(const short8v*)p; }
__device__ inline short8v cvt8f(const float* p) {   // 8 f32 -> 8 bf16
  f32x4 v0 = *(const f32x4*)p;
  f32x4 v1 = *(const f32x4*)(p + 4);
  short8v r;
#pragma unroll
  for (int j = 0; j < 4; ++j) { r[j] = (short)f2bf(v0[j]); r[4 + j] = (short)f2bf(v1[j]); }
  return r;
}
__device__ inline void gload_lds16(const u16* g, u16* l) {
  __builtin_amdgcn_global_load_lds(
      (const __attribute__((address_space(1))) void*)g,
      (__attribute__((address_space(3))) void*)l, 16, 0, 0);
}
// raw v_exp_f32 (2^x)
__device__ inline float exp2raw(float x) { return __builtin_amdgcn_exp2f(x); }
// v_cvt_pk_bf16_f32: dst.lo16 = bf16(a), dst.hi16 = bf16(b)  [T12/m240 recipe]
__device__ inline u32 pkbf(float a, float b) {
  u32 d; asm("v_cvt_pk_bf16_f32 %0, %1, %2" : "=v"(d) : "v"(a), "v"(b));
  return d;
}

// XOR swizzle for [.][64]-u16 LDS tiles (128 B rows) — r8..r20-proven.
__device__ inline int swz(int idx) {
  return idx ^ ((((idx >> 6) ^ (idx >> 9)) & 7) << 3);
}

// ---------------------------------------------------------------------------
// One-pass f32 -> bf16 conversion (unchanged, green).
// ---------------------------------------------------------------------------
__global__ __launch_bounds__(256) void cvt_all(
    const float* __restrict__ xq, const float* __restrict__ xk,
    const float* __restrict__ xv, const float* __restrict__ wq,
    const float* __restrict__ wk, const float* __restrict__ wv,
    const float* __restrict__ wo, u16* __restrict__ dst)
{
  int b = blockIdx.x;
  const float* s;
  u16* d;
  int local;
  if (b < 6144) {
    int which = b >> 11;
    s = (which == 0) ? xq : (which == 1) ? xk : xv;
    d = dst + (long)which * 4194304;
    local = b & 2047;
  } else {
    int wb = b - 6144;
    int which = wb >> 9;
    s = (which == 0) ? wq : (which == 1) ? wk : (which == 2) ? wv : wo;
    d = dst + 12582912 + (long)which * 1048576;
    local = wb & 511;
  }
  const long idx = ((long)local * 256 + threadIdx.x) * 8;
  *(short8v*)(d + idx) = cvt8f(s + idx);
}

// ---------------------------------------------------------------------------
// Pure-bf16 NT GEMM — r20 structure (green): 2-phase dbuf, BK=64, 128x64
// tile, z-indexed operand triples. NEW: per-z output scale (ascale) applied
// in the epilogue — used to fold the softmax 0.125*log2e into the Q-proj.
// ---------------------------------------------------------------------------
__global__ __launch_bounds__(256) void gemm_bf(
    const u16* __restrict__ A0, const u16* __restrict__ A1, const u16* __restrict__ A2,
    const u16* __restrict__ W0, const u16* __restrict__ W1, const u16* __restrict__ W2,
    void* __restrict__ C0, void* __restrict__ C1, void* __restrict__ C2,
    const float* __restrict__ bias, int CF32, float qscale, int Ndim, int Kdim)
{
  __shared__ __align__(16) u16 As[2][128 * 64];   // 2 x 16 KB
  __shared__ __align__(16) u16 Bs[2][64 * 64];    // 2 x  8 KB

  const int z = blockIdx.z;
  const u16* A = (z == 0) ? A0 : (z == 1) ? A1 : A2;
  const u16* W = (z == 0) ? W0 : (z == 1) ? W1 : W2;
  void* Craw   = (z == 0) ? C0 : (z == 1) ? C1 : C2;
  const float ascale = (z == 0) ? qscale : 1.0f;

  const int tid  = threadIdx.x;
  const int lane = tid & 63;
  const int w    = tid >> 6;
  const int wr   = w >> 1, wc = w & 1;
  const int r    = lane & 15, g = lane >> 4;

  const long brow = (long)blockIdx.x * 128;
  const long bcol = (long)blockIdx.y * 64;

  const int trow = tid >> 2;        // 0..63
  const int tk   = (tid & 3) * 8;   // 0,8,16,24

  const u16* Arow0 = A + (brow + trow) * (long)Kdim + tk;
  const u16* Arow1 = A + (brow + trow + 64) * (long)Kdim + tk;
  const u16* Wrow  = W + (bcol + trow) * (long)Kdim + tk;
  const int  woff  = w * 512;       // wave-uniform linear LDS dest (elems)

  f32x4 acc[4][2] = {};

  // prologue: stage k = 0..63 into buffer 0 (two 32-wide halves)
  gload_lds16(Arow0,      As[0] + woff);
  gload_lds16(Arow1,      As[0] + woff + 2048);
  gload_lds16(Arow0 + 32, As[0] + woff + 4096);
  gload_lds16(Arow1 + 32, As[0] + woff + 6144);
  gload_lds16(Wrow,       Bs[0] + woff);
  gload_lds16(Wrow + 32,  Bs[0] + woff + 2048);
  __syncthreads();   // drain vmcnt -> tile 0 visible

  int cur = 0;
  for (int k0 = 0; k0 < Kdim; k0 += 64) {
    if (k0 + 64 < Kdim) {
      const int kn = k0 + 64;
      gload_lds16(Arow0 + kn,      As[cur ^ 1] + woff);
      gload_lds16(Arow1 + kn,      As[cur ^ 1] + woff + 2048);
      gload_lds16(Arow0 + kn + 32, As[cur ^ 1] + woff + 4096);
      gload_lds16(Arow1 + kn + 32, As[cur ^ 1] + woff + 6144);
      gload_lds16(Wrow + kn,       Bs[cur ^ 1] + woff);
      gload_lds16(Wrow + kn + 32,  Bs[cur ^ 1] + woff + 2048);
    }

#pragma unroll
    for (int half = 0; half < 2; ++half) {
      const u16* Ah = As[cur] + half * 4096;
      const u16* Bh = Bs[cur] + half * 2048;
      short8v afr[4], bfr[2];
#pragma unroll
      for (int m = 0; m < 4; ++m)
        afr[m] = ld8(Ah + (wr * 64 + m * 16 + r) * 32 + g * 8);
#pragma unroll
      for (int n = 0; n < 2; ++n)
        bfr[n] = ld8(Bh + (wc * 32 + n * 16 + r) * 32 + g * 8);
#pragma unroll
      for (int m = 0; m < 4; ++m)
#pragma unroll
        for (int n = 0; n < 2; ++n)
          acc[m][n] = __builtin_amdgcn_mfma_f32_16x16x32_bf16(afr[m], bfr[n], acc[m][n], 0, 0, 0);
    }

    __syncthreads();   // next-tile loads drained; all readers of [cur] done
    cur ^= 1;
  }

#pragma unroll
  for (int n = 0; n < 2; ++n) {
    const long col = bcol + wc * 32 + n * 16 + r;
    const float bv = bias ? bias[col] : 0.0f;
#pragma unroll
    for (int m = 0; m < 4; ++m) {
#pragma unroll
      for (int r4 = 0; r4 < 4; ++r4) {
        const long row = brow + wr * 64 + m * 16 + g * 4 + r4;
        const float v = acc[m][n][r4] * ascale + bv;
        if (CF32) ((float*)Craw)[row * (long)Ndim + col] = v;
        else      ((u16*)Craw)[row * (long)Ndim + col]   = f2bf(v);
      }
    }
  }
}

// ---------------------------------------------------------------------------
// MFMA flash attention — EXACT r19/r20 structure (best green, 68 us), minus
// the softmax scale multiply (pre-folded into Q-proj): p = exp2raw(sf).
// Swapped QK^T, packed b64 P stores, XCD-pinned panels, 256 q-rows/block,
// dbuf K/V, max-free softmax.
// ---------------------------------------------------------------------------
__global__ __launch_bounds__(512) void attn_kernel(
    const u16* __restrict__ Q, const u16* __restrict__ K,
    const u16* __restrict__ V, const int* __restrict__ mask,
    u16* __restrict__ O)
{
  __shared__ __align__(16) u16 Ks[2][64 * 64];   // [key][d]   swizzled
  __shared__ __align__(16) u16 Vt[2][64 * 64];   // [d][key]   swizzled
  __shared__ __align__(16) u16 Ps[256 * 64];     // [q_local][key] swizzled

  const int tid  = threadIdx.x;
  const int lane = tid & 63;
  const int w    = tid >> 6;            // 0..7
  const int r    = lane & 15, g = lane >> 4;

  // XCD-aware decode: panels (b,h) pinned to one XCD (r18-proven)
  const int slot = blockIdx.x;          // 0..255
  const int p    = (slot & 7) + 8 * (slot >> 6);   // panel 0..31
  const int x    = (slot >> 3) & 7;                // q-tile 0..7
  const int h    = p & 15;
  const int b    = p >> 4;

  const long wq = (long)b * SEQ + (long)x * 256 + w * 32;

  short8v qf[2][2];
#pragma unroll
  for (int qt = 0; qt < 2; ++qt)
#pragma unroll
    for (int ks = 0; ks < 2; ++ks)
      qf[qt][ks] = ld8(Q + (wq + qt * 16 + r) * DMODEL + h * 64 + ks * 32 + g * 8);

  f32x4 of[2][4] = {};
  float lsum[2] = {0.f, 0.f};           // row-sum for q = wq + qt*16 + r

  const int trow = tid >> 3;            // 0..63 (full key coverage, 512 thr)
  const int td   = (tid & 7) * 8;       // 0..56

  const u16* Kb = K + (long)b * SEQ * DMODEL + h * 64;
  const u16* Vb = V + (long)b * SEQ * DMODEL + h * 64;
  const int* mb = mask + (long)b * SEQ;

  // prologue: stage tile 0 (each thread: one K row-piece, one V row-piece)
  {
    short8v k0v = ld8(Kb + (long)trow * DMODEL + td);
    short8v v0v = ld8(Vb + (long)trow * DMODEL + td);
    *(short8v*)(Ks[0] + swz(trow * 64 + td)) = k0v;
#pragma unroll
    for (int j = 0; j < 8; ++j)
      Vt[0][swz((td + j) * 64 + trow)] = (u16)v0v[j];
  }

  int cur = 0;

  for (int t = 0; t < SEQ / 64; ++t) {
    const int kt0 = t * 64;
    const bool more = (t < SEQ / 64 - 1);

    // mask for this tile: 4 consecutive keys per kt (this lane's g-group)
    int4v keepc[4];
#pragma unroll
    for (int kt = 0; kt < 4; ++kt)
      keepc[kt] = *(const int4v*)(mb + kt0 + kt * 16 + g * 4);

    // issue next-tile global loads early (hide HBM/L2 latency under compute)
    short8v nk0, nv0;
    if (more) {
      nk0 = ld8(Kb + (long)(kt0 + 64 + trow) * DMODEL + td);
      nv0 = ld8(Vb + (long)(kt0 + 64 + trow) * DMODEL + td);
    }

    __syncthreads();   // staged tile [cur] visible; prev-iter readers done

    const u16* Kc = Ks[cur];
    const u16* Vc = Vt[cur];

    // S^T = K Q^T (swapped operands): lane holds S[q=r][key=kt*16+g*4+r4]
    // (Q pre-scaled by 0.125*log2e in the projection epilogue)
    f32x4 sf[2][4] = {};
#pragma unroll
    for (int ks = 0; ks < 2; ++ks) {
      short8v kf[4];
#pragma unroll
      for (int kt = 0; kt < 4; ++kt)
        kf[kt] = ld8(Kc + swz((kt * 16 + r) * 64 + ks * 32 + g * 8));
#pragma unroll
      for (int qt = 0; qt < 2; ++qt)
#pragma unroll
        for (int kt = 0; kt < 4; ++kt)
          sf[qt][kt] = __builtin_amdgcn_mfma_f32_16x16x32_bf16(kf[kt], qf[qt][ks], sf[qt][kt], 0, 0, 0);
    }

    // max-free softmax (scale pre-folded): one packed b64 write per kt
#pragma unroll
    for (int qt = 0; qt < 2; ++qt) {
      const int prow = (w * 32 + qt * 16 + r) * 64;
#pragma unroll
      for (int kt = 0; kt < 4; ++kt) {
        float p0 = keepc[kt][0] ? exp2raw(sf[qt][kt][0]) : 0.f;
        float p1 = keepc[kt][1] ? exp2raw(sf[qt][kt][1]) : 0.f;
        float p2 = keepc[kt][2] ? exp2raw(sf[qt][kt][2]) : 0.f;
        float p3 = keepc[kt][3] ? exp2raw(sf[qt][kt][3]) : 0.f;
        union { u32 u[2]; short4v s; } pk;
        pk.u[0] = pkbf(p0, p1);
        pk.u[1] = pkbf(p2, p3);
        *(short4v*)(Ps + swz(prow + kt * 16 + g * 4)) = pk.s;
        lsum[qt] += (p0 + p1) + (p2 + p3);
      }
    }

    // O += P V  (vb reads shared by both q-tiles; same-wave Ps write->read)
#pragma unroll
    for (int ks = 0; ks < 2; ++ks) {
      short8v vb[4];
#pragma unroll
      for (int dt = 0; dt < 4; ++dt)
        vb[dt] = ld8(Vc + swz((dt * 16 + r) * 64 + ks * 32 + g * 8));
#pragma unroll
      for (int qt = 0; qt < 2; ++qt) {
        short8v pa = ld8(Ps + swz((w * 32 + qt * 16 + r) * 64 + ks * 32 + g * 8));
#pragma unroll
        for (int dt = 0; dt < 4; ++dt)
          of[qt][dt] = __builtin_amdgcn_mfma_f32_16x16x32_bf16(pa, vb[dt], of[qt][dt], 0, 0, 0);
      }
    }

    // stage tile t+1 into the other buffer
    if (more) {
      *(short8v*)(Ks[cur ^ 1] + swz(trow * 64 + td)) = nk0;
#pragma unroll
      for (int j = 0; j < 8; ++j)
        Vt[cur ^ 1][swz((td + j) * 64 + trow)] = (u16)nv0[j];
      cur ^= 1;
    }
  }

  // denominators: total(q=r) = reduce over g-groups; fetch totals for this
  // lane's 4 output rows (q = g*4 + r4) from lanes 0..15 (r12/r19-proven).
#pragma unroll
  for (int qt = 0; qt < 2; ++qt) {
    float s = lsum[qt];
    s += __shfl_xor(s, 16);
    s += __shfl_xor(s, 32);
#pragma unroll
    for (int r4 = 0; r4 < 4; ++r4) {
      const float d = __shfl(s, g * 4 + r4);
      const float rcp = (d > 0.f) ? (1.0f / d) : 0.0f;
#pragma unroll
      for (int dt = 0; dt < 4; ++dt) {
        const long row = wq + qt * 16 + g * 4 + r4;
        const int  col = h * 64 + dt * 16 + r;
        O[row * DMODEL + col] = f2bf(of[qt][dt][r4] * rcp);
      }
    }
  }
}

// ---------------------------------------------------------------------------
extern "C" void kernel_launch(void* const* d_in, const int* in_sizes, int n_in,
                              void* d_out, int out_size, void* d_ws, size_t ws_size,
                              hipStream_t stream) {
  const float* q_in = (const float*)d_in[0];
  const float* k_in = (const float*)d_in[1];
  const float* v_in = (const float*)d_in[2];
  const int*   mask = (const int*)d_in[3];
  const float* w_q  = (const float*)d_in[4];
  const float* w_k  = (const float*)d_in[5];
  const float* w_v  = (const float*)d_in[6];
  const float* w_o  = (const float*)d_in[7];
  const float* b_o  = (const float*)d_in[8];

  // ws layout (32 MB): [Xq 8M][Xk 8M][Xv 8M][WQ 2M][WK 2M][WV 2M][WO 2M]
  u16* S  = (u16*)d_ws;
  u16* Xq = S;
  u16* Xk = S + 4194304;
  u16* Xv = S + 8388608;
  u16* WQ = S + 12582912;
  u16* WK = S + 13631488;
  u16* WV = S + 14680064;
  u16* WO = S + 15728640;
  u16* Qw = (u16*)d_out;   // Q-proj lives in d_out until the final GEMM
  u16* Kw = Xq;            // K-proj overwrites Xq (dead after Q-proj)
  u16* Vw = Xk;            // V-proj overwrites Xk (dead after K-proj)
  u16* Cw = Xv;            // ctx overwrites Xv (dead after V-proj)

  dim3 blk(256);

  cvt_all<<<dim3(8192), blk, 0, stream>>>(q_in, k_in, v_in, w_q, w_k, w_v, w_o, S);

  // all three projections in ONE dispatch (z selects operand triple);
  // Q output pre-scaled by 0.125*log2e (folded softmax scale)
  dim3 pgrid(MROWS / 128, DMODEL / 64, 3);   // (32, 16, 3)
  gemm_bf<<<pgrid, blk, 0, stream>>>(Xq, Xk, Xv, WQ, WK, WV,
                                     Qw, Kw, Vw, nullptr, 0, SCALE_LOG2E,
                                     DMODEL, DMODEL);

  // 256 blocks (1/CU), 512 threads; XCD-aware slot decode inside
  attn_kernel<<<dim3(256), dim3(512), 0, stream>>>(Qw, Kw, Vw, mask, Cw);

  dim3 ggrid(MROWS / 128, DMODEL / 64, 1);
  gemm_bf<<<ggrid, blk, 0, stream>>>(Cw, Cw, Cw, WO, WO, WO,
                                     (float*)d_out, (float*)d_out, (float*)d_out,
                                     b_o, 1, 1.0f, DMODEL, DMODEL);
}